// Round 15
// baseline (316.796 us; speedup 1.0000x reference)
//
#include <hip/hip_runtime.h>
#include <float.h>
#include <limits.h>
#include <math.h>

namespace {

constexpr int NB = 8;
constexpr int SL = 2048;
constexpr int DIM = 128;
constexpr int PP = 64;
constexpr int KK = 64;
constexpr int ROWS = 128;                // score tile rows
constexpr int CTILE = 128;               // score tile cols
constexpr int NSTRIP = SL / ROWS;        // 16
constexpr int CSPLIT = 4;                // verified best
constexpr int NSLOT = NSTRIP * CSPLIT;   // 64 slots per batch
constexpr int CAP = 512;                 // per-block candidate buffer
constexpr int PROJ_ROWS = 32;            // rows per proj block
constexpr int NPROJ = NB * SL / PROJ_ROWS;  // 512 proj blocks
constexpr int NSCORE = CSPLIT * NB * NSTRIP; // 512 score blocks
constexpr int PROJ_PER_BATCH = 64;       // proj blocks per batch
constexpr float MARGIN = 4e-3f;          // >> 2x worst-case fp32 dot error

__device__ __forceinline__ bool cgt64(double v1, int i1, double v2, int i2) {
  return (v1 > v2) || (v1 == v2 && i1 < i2);
}
__device__ __forceinline__ bool cgt32(float v1, int i1, float v2, int i2) {
  return (v1 > v2) || (v1 == v2 && i1 < i2);
}

// Shared-memory overlay: one allocation sized by the score path (~76 KB);
// each path uses its own view. Paths are blockIdx-uniform -> no cross-path
// aliasing within a block.
union __align__(16) SMem {
  struct {
    float sQ[128 * 68];      // aliased by rval (double) after scoring
    float sK[128 * 68];
    float cval[CAP];
    int   cidx[CAP];
    float smax[256];
    int   spos_r[ROWS];
    int   spos_c[CTILE];
    int   cnt_sh, ovf, mcnt;
    float thresh;
  } sc;
  struct { float sx[PROJ_ROWS * DIM]; } pj;
  struct { int bytemode; int wsum[4]; } cp;
  struct { double sval[NSLOT * 16]; int sidx[NSLOT * 16]; } mg;
};

// R27: ALL THREE PHASES IN ONE LAUNCH. Ledger across R12-R26: score 70 +
// proj ~20 + merge ~12 = ~102us of kernel time vs 192us wall -> ~90us is
// inter-kernel launch gap/overhead. Fusion removes 2 launch boundaries and
// overlaps proj(batch j) with score(batch i<j). Sync: device-scope atomic
// counters (guide G16): producers do stores -> __threadfence() ->
// __syncthreads() -> tid0 atomicAdd; consumers tid0-spin on atomicAdd(p,0)
// -> __syncthreads() -> __threadfence() -> read. Block-id order
// (proj, compact, score, merge) matches dispatch order -> producers always
// dispatch before their consumers spin -> no deadlock.
// Compute bodies are VERBATIM from the verified best (R23 proj / R15 score /
// R12 merge) -> bit-identical output.
__global__ __launch_bounds__(256, 2) void fused_kernel(
    const float* __restrict__ x, const void* __restrict__ mask_raw,
    const float* __restrict__ Wq, const float* __restrict__ bq,
    const float* __restrict__ Wk, const float* __restrict__ bk,
    float* __restrict__ Q, float* __restrict__ K,
    int* __restrict__ pos, int* __restrict__ cnt,
    unsigned* __restrict__ ctr, unsigned* __restrict__ sdone,
    double* __restrict__ chunk_val, int* __restrict__ chunk_idx,
    float* __restrict__ out) {
  __shared__ SMem sm;
  const int bid = blockIdx.x;
  const int tid = threadIdx.x;
  const int lane = tid & 63;

  // ================= phase A: projection (R23-verified verbatim) =========
  if (bid < NPROJ) {
    float* sx = sm.pj.sx;
    const int row0 = bid * PROJ_ROWS;
    for (int t = tid; t < PROJ_ROWS * 32; t += 256) {
      const int row = t >> 5, f = t & 31;
      *(float4*)&sx[row * DIM + f * 4] =
          *(const float4*)(x + (size_t)(row0 + row) * DIM + f * 4);
    }
    __syncthreads();
    const int rq = tid >> 5;        // 8 row-quads: rows rq*4 .. rq*4+3
    const int pp = (tid & 31) * 2;  // same col-pair mapping as R12
    double aq[4][2] = {}, cq[4][2] = {}, ak[4][2] = {}, ck[4][2] = {};
    for (int d = 0; d < DIM; d += 4) {
      float4 xv[4];
#pragma unroll
      for (int i = 0; i < 4; ++i)
        xv[i] = *(const float4*)&sx[(rq * 4 + i) * DIM + d];
      const float2 wq0 = *(const float2*)&Wq[(d + 0) * PP + pp];
      const float2 wq1 = *(const float2*)&Wq[(d + 1) * PP + pp];
      const float2 wq2 = *(const float2*)&Wq[(d + 2) * PP + pp];
      const float2 wq3 = *(const float2*)&Wq[(d + 3) * PP + pp];
      const float2 wk0 = *(const float2*)&Wk[(d + 0) * PP + pp];
      const float2 wk1 = *(const float2*)&Wk[(d + 1) * PP + pp];
      const float2 wk2 = *(const float2*)&Wk[(d + 2) * PP + pp];
      const float2 wk3 = *(const float2*)&Wk[(d + 3) * PP + pp];
#pragma unroll
      for (int i = 0; i < 4; ++i) {
        const double x0 = (double)xv[i].x, x1 = (double)xv[i].y;
        const double x2 = (double)xv[i].z, x3 = (double)xv[i].w;
        aq[i][0] += x0 * (double)wq0.x; aq[i][1] += x0 * (double)wq0.y;
        cq[i][0] += x1 * (double)wq1.x; cq[i][1] += x1 * (double)wq1.y;
        aq[i][0] += x2 * (double)wq2.x; aq[i][1] += x2 * (double)wq2.y;
        cq[i][0] += x3 * (double)wq3.x; cq[i][1] += x3 * (double)wq3.y;
        ak[i][0] += x0 * (double)wk0.x; ak[i][1] += x0 * (double)wk0.y;
        ck[i][0] += x1 * (double)wk1.x; ck[i][1] += x1 * (double)wk1.y;
        ak[i][0] += x2 * (double)wk2.x; ak[i][1] += x2 * (double)wk2.y;
        ck[i][0] += x3 * (double)wk3.x; ck[i][1] += x3 * (double)wk3.y;
      }
    }
    const double b0q = (double)bq[pp], b1q = (double)bq[pp + 1];
    const double b0k = (double)bk[pp], b1k = (double)bk[pp + 1];
#pragma unroll
    for (int i = 0; i < 4; ++i) {
      const size_t o = ((size_t)row0 + rq * 4 + i) * PP + pp;
      Q[o]     = (float)(aq[i][0] + cq[i][0] + b0q);
      Q[o + 1] = (float)(aq[i][1] + cq[i][1] + b1q);
      K[o]     = (float)(ak[i][0] + ck[i][0] + b0k);
      K[o + 1] = (float)(ak[i][1] + ck[i][1] + b1k);
    }
    // signal: this batch's Q/K rows are globally visible
    __threadfence();
    __syncthreads();
    if (tid == 0) atomicAdd(&ctr[bid >> 6], 1u);
    return;
  }

  // ================= phase B: mask compact (verified verbatim) ===========
  if (bid < NPROJ + NB) {
    const int b = bid - NPROJ;
    const int wid = tid >> 6;
    if (tid == 0) sm.cp.bytemode = 0;
    __syncthreads();
    const unsigned char* allb = (const unsigned char*)mask_raw;
    int local = 0;
    for (int t = tid; t < 512; t += 256)
      if ((t & 3) != 0 && allb[t] != 0) local = 1;   // dtype probe
    if (local) atomicOr(&sm.cp.bytemode, 1);
    __syncthreads();
    int f[8]; int c = 0;
    const int base = tid * 8;
    if (sm.cp.bytemode) {
      const unsigned char* p = allb + (size_t)b * SL;
      for (int j = 0; j < 8; ++j) { f[j] = p[base + j] ? 1 : 0; c += f[j]; }
    } else {
      const int* p = (const int*)mask_raw + (size_t)b * SL;
      for (int j = 0; j < 8; ++j) { f[j] = p[base + j] ? 1 : 0; c += f[j]; }
    }
    int incl = c;
    for (int off = 1; off < 64; off <<= 1) {
      int t = __shfl_up(incl, off);
      if (lane >= off) incl += t;
    }
    if (lane == 63) sm.cp.wsum[wid] = incl;
    __syncthreads();
    int woff = 0;
    for (int w = 0; w < wid; ++w) woff += sm.cp.wsum[w];
    int k = woff + incl - c;
    for (int j = 0; j < 8; ++j)
      if (f[j]) pos[b * SL + (k++)] = base + j;
    if (tid == 255) cnt[b] = k;
    __threadfence();
    __syncthreads();
    if (tid == 0) atomicAdd(&ctr[b], 1u);
    return;
  }

  // ================= phase C: score (R15-verified verbatim body) =========
  if (bid < NPROJ + NB + NSCORE) {
    const int sid = bid - (NPROJ + NB);
    const int colq = sid & 3;            // == old blockIdx.x (CSPLIT)
    const int b = (sid >> 2) & 7;        // == old blockIdx.y (NB)
    const int strip = sid >> 5;          // == old blockIdx.z (NSTRIP, slowest)

    // wait for this batch's proj (64) + compact (1)
    if (tid == 0) {
      while (atomicAdd(&ctr[b], 0u) < (unsigned)(PROJ_PER_BATCH + 1))
        __builtin_amdgcn_s_sleep(8);
    }
    __syncthreads();
    __threadfence();

    float* sQ = sm.sc.sQ;
    float* sK = sm.sc.sK;
    const int nv = cnt[b];
    const int slot = (b * NSTRIP + strip) * CSPLIT + colq;
    const int r0 = strip * ROWS;
    const int per = (nv + CSPLIT - 1) / CSPLIT;
    const int cbeg = colq * per;
    const int cend = min(cbeg + per, nv);
    double* chv = chunk_val + (size_t)slot * KK;
    int* chi = chunk_idx + (size_t)slot * KK;
    if (r0 >= nv || cbeg >= cend) {
      if (tid < KK) { chv[tid] = -DBL_MAX; chi[tid] = INT_MAX; }
      __threadfence();
      __syncthreads();
      if (tid == 0) atomicAdd(&sdone[b], 1u);
      return;
    }
    const int nrows = min(ROWS, nv - r0);
    if (tid < ROWS) sm.sc.spos_r[tid] = (tid < nrows) ? pos[b * SL + r0 + tid] : 0;
    for (int t = tid; t < 128 * 16; t += 256) {
      const int row = t >> 4, p4 = t & 15;
      float4 v = make_float4(0.f, 0.f, 0.f, 0.f);
      if (row < nrows) {
        const int g = pos[b * SL + r0 + row];
        v = *(const float4*)(Q + ((size_t)b * SL + g) * PP + p4 * 4);
      }
      *(float4*)&sQ[row * 68 + p4 * 4] = v;
    }
    if (tid == 0) { sm.sc.cnt_sh = 0; sm.sc.ovf = 0; sm.sc.thresh = -FLT_MAX; }
    __syncthreads();

    const int ry = tid & 15, cy = tid >> 4;  // rows ry+16i, cols cy+16j (i,j<8)

    for (int c0 = cbeg; c0 < cend; c0 += CTILE) {
      const int ncols = min(CTILE, cend - c0);
      if (tid < CTILE) sm.sc.spos_c[tid] = (tid < ncols) ? pos[b * SL + c0 + tid] : 0;
      for (int t = tid; t < 128 * 16; t += 256) {
        const int col = t >> 4, p4 = t & 15;
        float4 v = make_float4(0.f, 0.f, 0.f, 0.f);
        if (col < ncols) {
          const int g = pos[b * SL + c0 + col];
          v = *(const float4*)(K + ((size_t)b * SL + g) * PP + p4 * 4);
        }
        *(float4*)&sK[col * 68 + p4 * 4] = v;
      }
      __syncthreads();

      float acc[8][8] = {};
      for (int p4 = 0; p4 < 16; ++p4) {
        float4 qv[8], kv[8];
#pragma unroll
        for (int i = 0; i < 8; ++i) qv[i] = *(const float4*)&sQ[(ry + 16 * i) * 68 + p4 * 4];
#pragma unroll
        for (int j = 0; j < 8; ++j) kv[j] = *(const float4*)&sK[(cy + 16 * j) * 68 + p4 * 4];
#pragma unroll
        for (int i = 0; i < 8; ++i)
#pragma unroll
          for (int j = 0; j < 8; ++j) {
            acc[i][j] = fmaf(qv[i].x, kv[j].x, acc[i][j]);
            acc[i][j] = fmaf(qv[i].y, kv[j].y, acc[i][j]);
            acc[i][j] = fmaf(qv[i].z, kv[j].z, acc[i][j]);
            acc[i][j] = fmaf(qv[i].w, kv[j].w, acc[i][j]);
          }
      }

      if (c0 == cbeg) {
        // ---- self-seed threshold from tile 0 (verified construction) ----
        float tmax = -FLT_MAX;
        for (int i = 0; i < 8; ++i) {
          const int rr = ry + 16 * i;
          if (rr >= nrows) continue;
          for (int j = 0; j < 8; ++j) {
            const int cc = cy + 16 * j;
            if (cc >= ncols) continue;
            tmax = fmaxf(tmax, acc[i][j] * 0.125f);
          }
        }
        sm.sc.smax[tid] = tmax;
        __syncthreads();
        for (int k2 = 2; k2 <= 256; k2 <<= 1)
          for (int j2 = k2 >> 1; j2 >= 1; j2 >>= 1) {
            if (tid < 128) {
              const int i = ((tid & ~(j2 - 1)) << 1) | (tid & (j2 - 1));
              const int p = i | j2;
              const bool desc = ((i & k2) == 0);
              const float vi = sm.sc.smax[i], vp = sm.sc.smax[p];
              const bool sw = desc ? (vp > vi) : (vi > vp);
              if (sw) { sm.sc.smax[i] = vp; sm.sc.smax[p] = vi; }
            }
            __syncthreads();
          }
        if (tid == 0 && sm.sc.smax[KK - 1] > -FLT_MAX)
          sm.sc.thresh = sm.sc.smax[KK - 1] - MARGIN;
        __syncthreads();
      }

      // wave-granular all-or-nothing emission; overflow -> compact + retry
      bool pushed = false;
      for (int attempt = 0; attempt < 8; ++attempt) {
        const float th = sm.sc.thresh;
        int nloc = 0;
        for (int i = 0; i < 8; ++i) {
          const int rr = ry + 16 * i;
          if (rr >= nrows) continue;
          for (int j = 0; j < 8; ++j) {
            const int cc = cy + 16 * j;
            if (cc >= ncols) continue;
            if (acc[i][j] * 0.125f >= th) nloc++;
          }
        }
        int incl = nloc;
        for (int off = 1; off < 64; off <<= 1) {
          int t2 = __shfl_up(incl, off);
          if (lane >= off) incl += t2;
        }
        const int wtot = __shfl(incl, 63);
        if (!pushed) {
          if (wtot == 0) {
            pushed = true;
          } else {
            int wbase = 0;
            if (lane == 63) {
              wbase = atomicAdd(&sm.sc.cnt_sh, wtot);
              if (wbase + wtot > CAP) { atomicAdd(&sm.sc.cnt_sh, -wtot); wbase = -1; sm.sc.ovf = 1; }
            }
            wbase = __shfl(wbase, 63);
            if (wbase >= 0) {
              int sl = wbase + incl - nloc;
              for (int i = 0; i < 8; ++i) {
                const int rr = ry + 16 * i;
                if (rr >= nrows) continue;
                for (int j = 0; j < 8; ++j) {
                  const int cc = cy + 16 * j;
                  if (cc >= ncols) continue;
                  const float s = acc[i][j] * 0.125f;
                  if (s >= th) {
                    sm.sc.cval[sl] = s;
                    sm.sc.cidx[sl] = sm.sc.spos_r[rr] * SL + sm.sc.spos_c[cc];
                    ++sl;
                  }
                }
              }
              pushed = true;
            }
          }
        }
        __syncthreads();
        if (sm.sc.ovf == 0) break;
        // ---- compaction (cold path, verified) ----
        {
          const int n = sm.sc.cnt_sh;
          for (int j = n + tid; j < CAP; j += 256) { sm.sc.cval[j] = -FLT_MAX; sm.sc.cidx[j] = INT_MAX; }
          __syncthreads();
          for (int k2 = 2; k2 <= CAP; k2 <<= 1)
            for (int j2 = k2 >> 1; j2 >= 1; j2 >>= 1) {
              const int i = ((tid & ~(j2 - 1)) << 1) | (tid & (j2 - 1));
              const int p = i | j2;
              const bool desc = ((i & k2) == 0);
              const float vi = sm.sc.cval[i], vp = sm.sc.cval[p];
              const int ii = sm.sc.cidx[i], ip = sm.sc.cidx[p];
              const bool sw = desc ? cgt32(vp, ip, vi, ii) : cgt32(vi, ii, vp, ip);
              if (sw) { sm.sc.cval[i] = vp; sm.sc.cidx[i] = ip; sm.sc.cval[p] = vi; sm.sc.cidx[p] = ii; }
              __syncthreads();
            }
          const float t64 = sm.sc.cval[KK - 1];
          const float nth = (t64 > -FLT_MAX) ? (t64 - MARGIN) : sm.sc.thresh;
          for (int j = tid; j < CAP; j += 256) {
            const bool in = (sm.sc.cidx[j] != INT_MAX) && (sm.sc.cval[j] >= nth);
            const bool nx = (j + 1 < CAP) && (sm.sc.cidx[j + 1] != INT_MAX) && (sm.sc.cval[j + 1] >= nth);
            if (in && !nx) sm.sc.mcnt = j + 1;
            if (j == 0 && !in) sm.sc.mcnt = 0;
          }
          __syncthreads();
          if (tid == 0) { sm.sc.thresh = nth; sm.sc.cnt_sh = sm.sc.mcnt; sm.sc.ovf = 0; }
          __syncthreads();
        }
      }
      __syncthreads();  // protect sK/spos_c restage
    }

    // ---- fp64 refine (8 threads/survivor, verified) ----
    const int n = sm.sc.cnt_sh;
    double* rval = (double*)sQ;  // alias: sQ dead after scoring
    for (int base2 = 0; base2 < n; base2 += 32) {
      const int s = base2 + (tid >> 3);
      double p = 0;
      if (s < n) {
        const int fi = sm.sc.cidx[s];
        const int orow = fi >> 11, ocol = fi & (SL - 1);
        const float* qr = Q + ((size_t)b * SL + orow) * PP + (tid & 7) * 8;
        const float* kr = K + ((size_t)b * SL + ocol) * PP + (tid & 7) * 8;
#pragma unroll
        for (int e = 0; e < 8; ++e) p = fma((double)qr[e], (double)kr[e], p);
      }
      p += __shfl_down(p, 4);
      p += __shfl_down(p, 2);
      p += __shfl_down(p, 1);
      if (((tid & 7) == 0) && s < n) rval[s] = p * 0.125;
    }
    // ---- adaptive LDS bitonic (verified) + top-64 out ----
    int np2 = KK;
    while (np2 < n) np2 <<= 1;  // n <= CAP
    for (int j = n + tid; j < np2; j += 256) { rval[j] = -DBL_MAX; sm.sc.cidx[j] = INT_MAX; }
    __syncthreads();
    for (int k2 = 2; k2 <= np2; k2 <<= 1)
      for (int j2 = k2 >> 1; j2 >= 1; j2 >>= 1) {
        if (tid < (np2 >> 1)) {
          const int i = ((tid & ~(j2 - 1)) << 1) | (tid & (j2 - 1));
          const int p = i | j2;
          const bool desc = ((i & k2) == 0);
          const double vi = rval[i], vp = rval[p];
          const int ii = sm.sc.cidx[i], ip = sm.sc.cidx[p];
          const bool sw = desc ? cgt64(vp, ip, vi, ii) : cgt64(vi, ii, vp, ip);
          if (sw) { rval[i] = vp; sm.sc.cidx[i] = ip; rval[p] = vi; sm.sc.cidx[p] = ii; }
        }
        __syncthreads();
      }
    if (tid < KK) { chv[tid] = rval[tid]; chi[tid] = sm.sc.cidx[tid]; }
    __threadfence();
    __syncthreads();
    if (tid == 0) atomicAdd(&sdone[b], 1u);
    return;
  }

  // ================= phase D: merge (R12-verified verbatim body) =========
  {
    const int b = bid - (NPROJ + NB + NSCORE);
    if (tid == 0) {
      while (atomicAdd(&sdone[b], 0u) < (unsigned)NSLOT)
        __builtin_amdgcn_s_sleep(8);
    }
    __syncthreads();
    __threadfence();

    const double* vb = chunk_val + (size_t)b * NSLOT * KK;
    const int* ib = chunk_idx + (size_t)b * NSLOT * KK;
    for (int t = tid; t < NSLOT * 16; t += 256) {
      const int list = t >> 4, e = t & 15;
      sm.mg.sval[t] = vb[list * KK + e];
      sm.mg.sidx[t] = ib[list * KK + e];
    }
    __syncthreads();
    if (tid < 64) {
      const int ln = tid;
      int hp = 0;
      double cur = sm.mg.sval[ln * 16];
      int curi = sm.mg.sidx[ln * 16];
      double myv = -DBL_MAX; int myi = INT_MAX;
      for (int k = 0; k < KK; ++k) {
        double bv = cur; int bi = curi; int bg = ln;
        for (int off2 = 32; off2 > 0; off2 >>= 1) {
          const double v2 = __shfl_down(bv, off2);
          const int i2 = __shfl_down(bi, off2);
          const int g2 = __shfl_down(bg, off2);
          if (cgt64(v2, i2, bv, bi)) { bv = v2; bi = i2; bg = g2; }
        }
        bv = __shfl(bv, 0); bi = __shfl(bi, 0); bg = __shfl(bg, 0);
        if (bg == ln) {
          const int h = ++hp;
          if (h < 16) { cur = sm.mg.sval[ln * 16 + h]; curi = sm.mg.sidx[ln * 16 + h]; }
          else if (h < KK) { cur = vb[ln * KK + h]; curi = ib[ln * KK + h]; }
          else { cur = -DBL_MAX; curi = INT_MAX; }
        }
        if (ln == k) { myv = bv; myi = bi; }
      }
      const double m = __shfl(myv, 0);
      double e = (myi == INT_MAX || myv == -DBL_MAX) ? 0.0 : exp(myv - m);
      double s = e;
      for (int off2 = 32; off2 > 0; off2 >>= 1) s += __shfl_down(s, off2);
      s = __shfl(s, 0);
      if (s <= 0.0) s = 1.0;
      const double w = e / s;
      int row = 0, col = 0;
      if (myi != INT_MAX) { row = myi >> 11; col = myi & (SL - 1); }
      float* oidx = out;
      float* owt = out + (size_t)NB * KK * 2;
      oidx[((size_t)b * KK + ln) * 2 + 0] = (float)row;
      oidx[((size_t)b * KK + ln) * 2 + 1] = (float)col;
      owt[(size_t)b * KK + ln] = (float)w;
    }
  }
}

}  // namespace

extern "C" void kernel_launch(void* const* d_in, const int* in_sizes, int n_in,
                              void* d_out, int out_size, void* d_ws, size_t ws_size,
                              hipStream_t stream) {
  const float* x = (const float*)d_in[0];
  const void* mask_raw = d_in[1];
  const float* Wq = (const float*)d_in[2];
  const float* bq = (const float*)d_in[3];
  const float* Wk = (const float*)d_in[4];
  const float* bk = (const float*)d_in[5];
  float* out = (float*)d_out;

  char* ws = (char*)d_ws;
  const size_t qk = (size_t)NB * SL * PP;  // 1,048,576 elems
  float* Q = (float*)ws;                                            // 4 MB
  float* K = (float*)(ws + qk * 4);                                 // 4 MB
  size_t off = qk * 8;
  double* chunk_val = (double*)(ws + off); off += (size_t)NB * NSLOT * KK * 8;  // 256 KB
  int* chunk_idx = (int*)(ws + off);       off += (size_t)NB * NSLOT * KK * 4;  // 128 KB
  int* pos = (int*)(ws + off);             off += (size_t)NB * SL * 4;          // 64 KB
  int* cntv = (int*)(ws + off);            off += NB * sizeof(int);
  unsigned* ctr = (unsigned*)(ws + off);   off += NB * sizeof(unsigned);
  unsigned* sdone = (unsigned*)(ws + off); // total ~8.45 MB

  // zero the sync counters (ctr[8] + sdone[8] = 64 B), stream-ordered,
  // graph-capture-safe (async op on the provided stream).
  hipMemsetAsync(ctr, 0, 2 * NB * sizeof(unsigned), stream);

  // One launch: proj(512) | compact(8) | score(512, R15 packing order) |
  // merge(8). Producers precede consumers in dispatch order.
  fused_kernel<<<NPROJ + NB + NSCORE + NB, 256, 0, stream>>>(
      x, mask_raw, Wq, bq, Wk, bk, Q, K, pos, cntv, ctr, sdone,
      chunk_val, chunk_idx, out);
}

// Round 16
// 195.568 us; speedup vs baseline: 1.6199x; 1.6199x over previous
//
#include <hip/hip_runtime.h>
#include <float.h>
#include <limits.h>
#include <math.h>

namespace {

constexpr int NB = 8;
constexpr int SL = 2048;
constexpr int DIM = 128;
constexpr int PP = 64;
constexpr int KK = 64;
constexpr int ROWS = 128;                // score tile rows
constexpr int CTILE = 128;               // score tile cols
constexpr int NSTRIP = SL / ROWS;        // 16
constexpr int CSPLIT = 4;                // verified best
constexpr int NSLOT = NSTRIP * CSPLIT;   // 64 slots per batch
constexpr int CAP = 512;                 // per-block candidate buffer
constexpr int PROJ_ROWS = 64;            // R28: 64 rows/block, 8 rows/thread
constexpr int NPROJ = NB * SL / PROJ_ROWS;  // 256 proj blocks
constexpr float MARGIN = 4e-3f;          // >> 2x worst-case fp32 dot error

__device__ __forceinline__ bool cgt64(double v1, int i1, double v2, int i2) {
  return (v1 > v2) || (v1 == v2 && i1 < i2);
}
__device__ __forceinline__ bool cgt32(float v1, int i1, float v2, int i2) {
  return (v1 > v2) || (v1 == v2 && i1 < i2);
}

// Blocks [0,NPROJ): Q/K projection.
// R28: 8 ROWS/THREAD (PROJ_ROWS=64). Causal evidence for this axis:
// R23 (W direct from L2) helped; R24 (2 rows/thread = W-loads-per-output
// x2) hurt +14us. Going the other way: 256 W float2 loads/thread now
// amortize over 32 outputs (2x R23). Per d-step: 128 fp64 FMAs vs 8 W
// loads + 8 LDS reads -> compute-dominated; 64 independent acc chains give
// the ILP so 1 block/CU suffices. Per-output chain (even/odd-d order,
// (a+c)+bias finish, same W/x addresses) computed by ONE thread in the
// SAME order -> Q/K BIT-IDENTICAL to R10..R23. VGPR ~200 under
// __launch_bounds__(256,1) (512 cap) -> no spill.
// Blocks [NPROJ, NPROJ+NB): mask canonicalize + compact (verified verbatim).
__global__ __launch_bounds__(256, 1) void proj_compact_kernel(
    const float* __restrict__ x, const void* __restrict__ mask_raw,
    const float* __restrict__ Wq, const float* __restrict__ bq,
    const float* __restrict__ Wk, const float* __restrict__ bk,
    float* __restrict__ Q, float* __restrict__ K,
    int* __restrict__ pos, int* __restrict__ cnt) {
  const int tid = threadIdx.x;
  if (blockIdx.x >= NPROJ) {
    const int b = blockIdx.x - NPROJ;
    const int lane = tid & 63, wid = tid >> 6;
    __shared__ int bytemode;
    __shared__ int wsum[4];
    if (tid == 0) bytemode = 0;
    __syncthreads();
    const unsigned char* allb = (const unsigned char*)mask_raw;
    int local = 0;
    for (int t = tid; t < 512; t += 256)
      if ((t & 3) != 0 && allb[t] != 0) local = 1;   // dtype probe
    if (local) atomicOr(&bytemode, 1);
    __syncthreads();
    int f[8]; int c = 0;
    const int base = tid * 8;
    if (bytemode) {
      const unsigned char* p = allb + (size_t)b * SL;
      for (int j = 0; j < 8; ++j) { f[j] = p[base + j] ? 1 : 0; c += f[j]; }
    } else {
      const int* p = (const int*)mask_raw + (size_t)b * SL;
      for (int j = 0; j < 8; ++j) { f[j] = p[base + j] ? 1 : 0; c += f[j]; }
    }
    int incl = c;
    for (int off = 1; off < 64; off <<= 1) {
      int t = __shfl_up(incl, off);
      if (lane >= off) incl += t;
    }
    if (lane == 63) wsum[wid] = incl;
    __syncthreads();
    int woff = 0;
    for (int w = 0; w < wid; ++w) woff += wsum[w];
    int k = woff + incl - c;
    for (int j = 0; j < 8; ++j)
      if (f[j]) pos[b * SL + (k++)] = base + j;
    if (tid == 255) cnt[b] = k;
    return;
  }
  __shared__ __align__(16) float sx[PROJ_ROWS * DIM];  // 32 KB (x only)
  const int row0 = blockIdx.x * PROJ_ROWS;
  for (int t = tid; t < PROJ_ROWS * 32; t += 256) {
    const int row = t >> 5, f = t & 31;
    *(float4*)&sx[row * DIM + f * 4] =
        *(const float4*)(x + (size_t)(row0 + row) * DIM + f * 4);
  }
  __syncthreads();
  const int rq = tid >> 5;        // 8 row-octets: rows rq*8 .. rq*8+7
  const int pp = (tid & 31) * 2;  // same col-pair mapping as R12
  double aq[8][2] = {}, cq[8][2] = {}, ak[8][2] = {}, ck[8][2] = {};
  for (int d = 0; d < DIM; d += 4) {
    float4 xv[8];
#pragma unroll
    for (int i = 0; i < 8; ++i)
      xv[i] = *(const float4*)&sx[(rq * 8 + i) * DIM + d];
    // W read direct from global (L1/L2-resident): same values, same order
    // as staged copies -> bit-identical chains.
    const float2 wq0 = *(const float2*)&Wq[(d + 0) * PP + pp];
    const float2 wq1 = *(const float2*)&Wq[(d + 1) * PP + pp];
    const float2 wq2 = *(const float2*)&Wq[(d + 2) * PP + pp];
    const float2 wq3 = *(const float2*)&Wq[(d + 3) * PP + pp];
    const float2 wk0 = *(const float2*)&Wk[(d + 0) * PP + pp];
    const float2 wk1 = *(const float2*)&Wk[(d + 1) * PP + pp];
    const float2 wk2 = *(const float2*)&Wk[(d + 2) * PP + pp];
    const float2 wk3 = *(const float2*)&Wk[(d + 3) * PP + pp];
#pragma unroll
    for (int i = 0; i < 8; ++i) {
      const double x0 = (double)xv[i].x, x1 = (double)xv[i].y;
      const double x2 = (double)xv[i].z, x3 = (double)xv[i].w;
      aq[i][0] += x0 * (double)wq0.x; aq[i][1] += x0 * (double)wq0.y;
      cq[i][0] += x1 * (double)wq1.x; cq[i][1] += x1 * (double)wq1.y;
      aq[i][0] += x2 * (double)wq2.x; aq[i][1] += x2 * (double)wq2.y;
      cq[i][0] += x3 * (double)wq3.x; cq[i][1] += x3 * (double)wq3.y;
      ak[i][0] += x0 * (double)wk0.x; ak[i][1] += x0 * (double)wk0.y;
      ck[i][0] += x1 * (double)wk1.x; ck[i][1] += x1 * (double)wk1.y;
      ak[i][0] += x2 * (double)wk2.x; ak[i][1] += x2 * (double)wk2.y;
      ck[i][0] += x3 * (double)wk3.x; ck[i][1] += x3 * (double)wk3.y;
    }
  }
  const double b0q = (double)bq[pp], b1q = (double)bq[pp + 1];
  const double b0k = (double)bk[pp], b1k = (double)bk[pp + 1];
#pragma unroll
  for (int i = 0; i < 8; ++i) {
    const size_t o = ((size_t)row0 + rq * 8 + i) * PP + pp;
    Q[o]     = (float)(aq[i][0] + cq[i][0] + b0q);
    Q[o + 1] = (float)(aq[i][1] + cq[i][1] + b1q);
    K[o]     = (float)(ak[i][0] + ck[i][0] + b0k);
    K[o + 1] = (float)(ak[i][1] + ck[i][1] + b1k);
  }
}

// R12/R15-VERIFIED VERBATIM score body (256 threads, 8x8 micro-tile,
// CSPLIT=4, strip = blockIdx.z slowest). 70us = established floor for this
// structure (R13/R16/R17/R19/R26 all regressed vs it).
__global__ __launch_bounds__(256, 2) void score_kernel(
    const float* __restrict__ Q, const float* __restrict__ K,
    const int* __restrict__ pos, const int* __restrict__ cnt,
    double* __restrict__ chunk_val, int* __restrict__ chunk_idx) {
  __shared__ __align__(16) float sQ[128 * 68];   // aliased by rval after scoring
  __shared__ __align__(16) float sK[128 * 68];
  __shared__ float cval[CAP];
  __shared__ int cidx[CAP];
  __shared__ float smax[256];
  __shared__ int spos_r[ROWS], spos_c[CTILE];
  __shared__ int cnt_sh, ovf, mcnt;
  __shared__ float thresh;

  const int b = blockIdx.y, strip = blockIdx.z, colq = blockIdx.x;
  const int tid = threadIdx.x, lane = tid & 63;
  const int nv = cnt[b];
  const int slot = (b * NSTRIP + strip) * CSPLIT + colq;
  const int r0 = strip * ROWS;
  const int per = (nv + CSPLIT - 1) / CSPLIT;
  const int cbeg = colq * per;
  const int cend = min(cbeg + per, nv);
  double* chv = chunk_val + (size_t)slot * KK;
  int* chi = chunk_idx + (size_t)slot * KK;
  if (r0 >= nv || cbeg >= cend) {
    if (tid < KK) { chv[tid] = -DBL_MAX; chi[tid] = INT_MAX; }
    return;
  }
  const int nrows = min(ROWS, nv - r0);
  if (tid < ROWS) spos_r[tid] = (tid < nrows) ? pos[b * SL + r0 + tid] : 0;
  for (int t = tid; t < 128 * 16; t += 256) {
    const int row = t >> 4, p4 = t & 15;
    float4 v = make_float4(0.f, 0.f, 0.f, 0.f);
    if (row < nrows) {
      const int g = pos[b * SL + r0 + row];
      v = *(const float4*)(Q + ((size_t)b * SL + g) * PP + p4 * 4);
    }
    *(float4*)&sQ[row * 68 + p4 * 4] = v;
  }
  if (tid == 0) { cnt_sh = 0; ovf = 0; thresh = -FLT_MAX; }
  __syncthreads();

  const int ry = tid & 15, cy = tid >> 4;   // rows ry+16i, cols cy+16j (i,j<8)

  for (int c0 = cbeg; c0 < cend; c0 += CTILE) {
    const int ncols = min(CTILE, cend - c0);
    if (tid < CTILE) spos_c[tid] = (tid < ncols) ? pos[b * SL + c0 + tid] : 0;
    for (int t = tid; t < 128 * 16; t += 256) {
      const int col = t >> 4, p4 = t & 15;
      float4 v = make_float4(0.f, 0.f, 0.f, 0.f);
      if (col < ncols) {
        const int g = pos[b * SL + c0 + col];
        v = *(const float4*)(K + ((size_t)b * SL + g) * PP + p4 * 4);
      }
      *(float4*)&sK[col * 68 + p4 * 4] = v;
    }
    __syncthreads();

    float acc[8][8] = {};
    for (int p4 = 0; p4 < 16; ++p4) {
      float4 qv[8], kv[8];
#pragma unroll
      for (int i = 0; i < 8; ++i) qv[i] = *(const float4*)&sQ[(ry + 16 * i) * 68 + p4 * 4];
#pragma unroll
      for (int j = 0; j < 8; ++j) kv[j] = *(const float4*)&sK[(cy + 16 * j) * 68 + p4 * 4];
#pragma unroll
      for (int i = 0; i < 8; ++i)
#pragma unroll
        for (int j = 0; j < 8; ++j) {
          acc[i][j] = fmaf(qv[i].x, kv[j].x, acc[i][j]);
          acc[i][j] = fmaf(qv[i].y, kv[j].y, acc[i][j]);
          acc[i][j] = fmaf(qv[i].z, kv[j].z, acc[i][j]);
          acc[i][j] = fmaf(qv[i].w, kv[j].w, acc[i][j]);
        }
    }

    if (c0 == cbeg) {
      // ---- self-seed threshold from tile 0 (verified construction) ----
      float tmax = -FLT_MAX;
      for (int i = 0; i < 8; ++i) {
        const int rr = ry + 16 * i;
        if (rr >= nrows) continue;
        for (int j = 0; j < 8; ++j) {
          const int cc = cy + 16 * j;
          if (cc >= ncols) continue;
          tmax = fmaxf(tmax, acc[i][j] * 0.125f);
        }
      }
      smax[tid] = tmax;
      __syncthreads();
      for (int k2 = 2; k2 <= 256; k2 <<= 1)
        for (int j2 = k2 >> 1; j2 >= 1; j2 >>= 1) {
          if (tid < 128) {
            const int i = ((tid & ~(j2 - 1)) << 1) | (tid & (j2 - 1));
            const int p = i | j2;
            const bool desc = ((i & k2) == 0);
            const float vi = smax[i], vp = smax[p];
            const bool sw = desc ? (vp > vi) : (vi > vp);
            if (sw) { smax[i] = vp; smax[p] = vi; }
          }
          __syncthreads();
        }
      if (tid == 0 && smax[KK - 1] > -FLT_MAX) thresh = smax[KK - 1] - MARGIN;
      __syncthreads();
    }

    // wave-granular all-or-nothing emission; overflow -> compact + retry
    bool pushed = false;
    for (int attempt = 0; attempt < 8; ++attempt) {
      const float th = thresh;
      int nloc = 0;
      for (int i = 0; i < 8; ++i) {
        const int rr = ry + 16 * i;
        if (rr >= nrows) continue;
        for (int j = 0; j < 8; ++j) {
          const int cc = cy + 16 * j;
          if (cc >= ncols) continue;
          if (acc[i][j] * 0.125f >= th) nloc++;
        }
      }
      int incl = nloc;
      for (int off = 1; off < 64; off <<= 1) {
        int t2 = __shfl_up(incl, off);
        if (lane >= off) incl += t2;
      }
      const int wtot = __shfl(incl, 63);
      if (!pushed) {
        if (wtot == 0) {
          pushed = true;
        } else {
          int wbase = 0;
          if (lane == 63) {
            wbase = atomicAdd(&cnt_sh, wtot);
            if (wbase + wtot > CAP) { atomicAdd(&cnt_sh, -wtot); wbase = -1; ovf = 1; }
          }
          wbase = __shfl(wbase, 63);
          if (wbase >= 0) {
            int sl = wbase + incl - nloc;
            for (int i = 0; i < 8; ++i) {
              const int rr = ry + 16 * i;
              if (rr >= nrows) continue;
              for (int j = 0; j < 8; ++j) {
                const int cc = cy + 16 * j;
                if (cc >= ncols) continue;
                const float s = acc[i][j] * 0.125f;
                if (s >= th) {
                  cval[sl] = s;
                  cidx[sl] = spos_r[rr] * SL + spos_c[cc];
                  ++sl;
                }
              }
            }
            pushed = true;
          }
        }
      }
      __syncthreads();
      if (ovf == 0) break;
      // ---- compaction (cold path, verified): sort fp32 buffer, raise thresh ----
      {
        const int n = cnt_sh;
        for (int j = n + tid; j < CAP; j += 256) { cval[j] = -FLT_MAX; cidx[j] = INT_MAX; }
        __syncthreads();
        for (int k2 = 2; k2 <= CAP; k2 <<= 1)
          for (int j2 = k2 >> 1; j2 >= 1; j2 >>= 1) {
            const int i = ((tid & ~(j2 - 1)) << 1) | (tid & (j2 - 1));
            const int p = i | j2;
            const bool desc = ((i & k2) == 0);
            const float vi = cval[i], vp = cval[p];
            const int ii = cidx[i], ip = cidx[p];
            const bool sw = desc ? cgt32(vp, ip, vi, ii) : cgt32(vi, ii, vp, ip);
            if (sw) { cval[i] = vp; cidx[i] = ip; cval[p] = vi; cidx[p] = ii; }
            __syncthreads();
          }
        const float t64 = cval[KK - 1];
        const float nth = (t64 > -FLT_MAX) ? (t64 - MARGIN) : thresh;
        for (int j = tid; j < CAP; j += 256) {
          const bool in = (cidx[j] != INT_MAX) && (cval[j] >= nth);
          const bool nx = (j + 1 < CAP) && (cidx[j + 1] != INT_MAX) && (cval[j + 1] >= nth);
          if (in && !nx) mcnt = j + 1;
          if (j == 0 && !in) mcnt = 0;
        }
        __syncthreads();
        if (tid == 0) { thresh = nth; cnt_sh = mcnt; ovf = 0; }
        __syncthreads();
      }
    }
    __syncthreads();  // protect sK/spos_c restage
  }

  // ---- fp64 refine (8 threads/survivor, verified) ----
  const int n = cnt_sh;
  double* rval = (double*)sQ;  // alias: sQ dead after scoring
  for (int base2 = 0; base2 < n; base2 += 32) {
    const int s = base2 + (tid >> 3);
    double p = 0;
    if (s < n) {
      const int fi = cidx[s];
      const int orow = fi >> 11, ocol = fi & (SL - 1);
      const float* qr = Q + ((size_t)b * SL + orow) * PP + (tid & 7) * 8;
      const float* kr = K + ((size_t)b * SL + ocol) * PP + (tid & 7) * 8;
#pragma unroll
      for (int e = 0; e < 8; ++e) p = fma((double)qr[e], (double)kr[e], p);
    }
    p += __shfl_down(p, 4);
    p += __shfl_down(p, 2);
    p += __shfl_down(p, 1);
    if (((tid & 7) == 0) && s < n) rval[s] = p * 0.125;
  }
  // ---- adaptive LDS bitonic (verified) + top-64 out ----
  int np2 = KK;
  while (np2 < n) np2 <<= 1;  // n <= CAP
  for (int j = n + tid; j < np2; j += 256) { rval[j] = -DBL_MAX; cidx[j] = INT_MAX; }
  __syncthreads();
  for (int k2 = 2; k2 <= np2; k2 <<= 1)
    for (int j2 = k2 >> 1; j2 >= 1; j2 >>= 1) {
      if (tid < (np2 >> 1)) {
        const int i = ((tid & ~(j2 - 1)) << 1) | (tid & (j2 - 1));
        const int p = i | j2;
        const bool desc = ((i & k2) == 0);
        const double vi = rval[i], vp = rval[p];
        const int ii = cidx[i], ip = cidx[p];
        const bool sw = desc ? cgt64(vp, ip, vi, ii) : cgt64(vi, ii, vp, ip);
        if (sw) { rval[i] = vp; cidx[i] = ip; rval[p] = vi; cidx[p] = ii; }
      }
      __syncthreads();
    }
  if (tid < KK) { chv[tid] = rval[tid]; chi[tid] = cidx[tid]; }
}

// R11/R12-VERIFIED VERBATIM. 64-way merge of sorted lists, fp64 softmax, outputs.
__global__ __launch_bounds__(256) void merge_kernel(
    const double* __restrict__ chunk_val, const int* __restrict__ chunk_idx,
    float* __restrict__ out) {
  __shared__ double sval[NSLOT * 16];
  __shared__ int sidx[NSLOT * 16];
  const int b = blockIdx.x, tid = threadIdx.x;
  const double* vb = chunk_val + (size_t)b * NSLOT * KK;
  const int* ib = chunk_idx + (size_t)b * NSLOT * KK;
  for (int t = tid; t < NSLOT * 16; t += 256) {
    const int list = t >> 4, e = t & 15;
    sval[t] = vb[list * KK + e];
    sidx[t] = ib[list * KK + e];
  }
  __syncthreads();
  if (tid < 64) {
    const int lane = tid;
    int hp = 0;
    double cur = sval[lane * 16];
    int curi = sidx[lane * 16];
    double myv = -DBL_MAX; int myi = INT_MAX;
    for (int k = 0; k < KK; ++k) {
      double bv = cur; int bi = curi; int bg = lane;
      for (int off2 = 32; off2 > 0; off2 >>= 1) {
        const double v2 = __shfl_down(bv, off2);
        const int i2 = __shfl_down(bi, off2);
        const int g2 = __shfl_down(bg, off2);
        if (cgt64(v2, i2, bv, bi)) { bv = v2; bi = i2; bg = g2; }
      }
      bv = __shfl(bv, 0); bi = __shfl(bi, 0); bg = __shfl(bg, 0);
      if (bg == lane) {
        const int h = ++hp;
        if (h < 16) { cur = sval[lane * 16 + h]; curi = sidx[lane * 16 + h]; }
        else if (h < KK) { cur = vb[lane * KK + h]; curi = ib[lane * KK + h]; }
        else { cur = -DBL_MAX; curi = INT_MAX; }
      }
      if (lane == k) { myv = bv; myi = bi; }
    }
    const double m = __shfl(myv, 0);
    double e = (myi == INT_MAX || myv == -DBL_MAX) ? 0.0 : exp(myv - m);
    double s = e;
    for (int off2 = 32; off2 > 0; off2 >>= 1) s += __shfl_down(s, off2);
    s = __shfl(s, 0);
    if (s <= 0.0) s = 1.0;
    const double w = e / s;
    int row = 0, col = 0;
    if (myi != INT_MAX) { row = myi >> 11; col = myi & (SL - 1); }
    float* oidx = out;
    float* owt = out + (size_t)NB * KK * 2;
    oidx[((size_t)b * KK + lane) * 2 + 0] = (float)row;
    oidx[((size_t)b * KK + lane) * 2 + 1] = (float)col;
    owt[(size_t)b * KK + lane] = (float)w;
  }
}

}  // namespace

extern "C" void kernel_launch(void* const* d_in, const int* in_sizes, int n_in,
                              void* d_out, int out_size, void* d_ws, size_t ws_size,
                              hipStream_t stream) {
  const float* x = (const float*)d_in[0];
  const void* mask_raw = d_in[1];
  const float* Wq = (const float*)d_in[2];
  const float* bq = (const float*)d_in[3];
  const float* Wk = (const float*)d_in[4];
  const float* bk = (const float*)d_in[5];
  float* out = (float*)d_out;

  char* ws = (char*)d_ws;
  const size_t qk = (size_t)NB * SL * PP;  // 1,048,576 elems
  float* Q = (float*)ws;                                            // 4 MB
  float* K = (float*)(ws + qk * 4);                                 // 4 MB
  size_t off = qk * 8;
  double* chunk_val = (double*)(ws + off); off += (size_t)NB * NSLOT * KK * 8;  // 256 KB
  int* chunk_idx = (int*)(ws + off);       off += (size_t)NB * NSLOT * KK * 4;  // 128 KB
  int* pos = (int*)(ws + off);             off += (size_t)NB * SL * 4;          // 64 KB
  int* cntv = (int*)(ws + off);            // total ~8.45 MB

  // R28 proj: 64 rows/block, 8 rows/thread (W-loads amortized 2x vs R23).
  proj_compact_kernel<<<NPROJ + NB, 256, 0, stream>>>(
      x, mask_raw, Wq, bq, Wk, bk, Q, K, pos, cntv);
  // R15 packing (verified best): strip = blockIdx.z (slowest) -> active
  // blocks contiguous in dispatch order, spread 1-per-CU.
  score_kernel<<<dim3(CSPLIT, NB, NSTRIP), 256, 0, stream>>>(
      Q, K, pos, cntv, chunk_val, chunk_idx);
  merge_kernel<<<NB, 256, 0, stream>>>(chunk_val, chunk_idx, out);
}

// Round 17
// 192.016 us; speedup vs baseline: 1.6498x; 1.0185x over previous
//
#include <hip/hip_runtime.h>
#include <float.h>
#include <limits.h>
#include <math.h>

namespace {

constexpr int NB = 8;
constexpr int SL = 2048;
constexpr int DIM = 128;
constexpr int PP = 64;
constexpr int KK = 64;
constexpr int ROWS = 128;                // score tile rows
constexpr int CTILE = 128;               // score tile cols
constexpr int NSTRIP = SL / ROWS;        // 16
constexpr int CSPLIT = 4;                // verified best
constexpr int NSLOT = NSTRIP * CSPLIT;   // 64 slots per batch
constexpr int CAP = 512;                 // per-block candidate buffer
constexpr int PROJ_ROWS = 32;            // rows per proj block (R23-verified best:
                                         // 4 rows/thread; 2 and 8 both regressed)
constexpr int NPROJ = NB * SL / PROJ_ROWS;  // 512 proj blocks
constexpr float MARGIN = 4e-3f;          // >> 2x worst-case fp32 dot error

__device__ __forceinline__ bool cgt64(double v1, int i1, double v2, int i2) {
  return (v1 > v2) || (v1 == v2 && i1 < i2);
}
__device__ __forceinline__ bool cgt32(float v1, int i1, float v2, int i2) {
  return (v1 > v2) || (v1 == v2 && i1 < i2);
}

// FINAL (R29 = R23 verbatim, the harness-verified session best at 191.8us).
// Session ledger: R15 packing (-8us) and R23 proj de-staging (-6.5us) were
// the only wins; all other structural levers measured negative:
//   score ILP (R13/R19), 512t TLP (R17), co-residency (R16/R26), MFMA filter
//   (R21/22, layout bug unresolved), CSPLIT 2/8 (R20/R16), proj rows 2/8
//   (R24/R28), merge full-staging (R25), single-launch fusion (R27).
// score=70us is the structural floor of this algorithm shape (latency-bound,
// 1 wave/SIMD, VALUBusy ~22%); ~50us of wall is fixed harness overhead
// (measured in R27).
//
// Blocks [0,NPROJ): Q/K projection, 32 rows/block, 4 rows/thread, W read
// direct from global (L1/L2-resident; same values/order as staged copies ->
// fp64 chains BIT-IDENTICAL to R10..R12 lineage).
// Blocks [NPROJ, NPROJ+NB): mask canonicalize + compact (verified).
__global__ __launch_bounds__(256) void proj_compact_kernel(
    const float* __restrict__ x, const void* __restrict__ mask_raw,
    const float* __restrict__ Wq, const float* __restrict__ bq,
    const float* __restrict__ Wk, const float* __restrict__ bk,
    float* __restrict__ Q, float* __restrict__ K,
    int* __restrict__ pos, int* __restrict__ cnt) {
  const int tid = threadIdx.x;
  if (blockIdx.x >= NPROJ) {
    const int b = blockIdx.x - NPROJ;
    const int lane = tid & 63, wid = tid >> 6;
    __shared__ int bytemode;
    __shared__ int wsum[4];
    if (tid == 0) bytemode = 0;
    __syncthreads();
    const unsigned char* allb = (const unsigned char*)mask_raw;
    int local = 0;
    for (int t = tid; t < 512; t += 256)
      if ((t & 3) != 0 && allb[t] != 0) local = 1;   // dtype probe
    if (local) atomicOr(&bytemode, 1);
    __syncthreads();
    int f[8]; int c = 0;
    const int base = tid * 8;
    if (bytemode) {
      const unsigned char* p = allb + (size_t)b * SL;
      for (int j = 0; j < 8; ++j) { f[j] = p[base + j] ? 1 : 0; c += f[j]; }
    } else {
      const int* p = (const int*)mask_raw + (size_t)b * SL;
      for (int j = 0; j < 8; ++j) { f[j] = p[base + j] ? 1 : 0; c += f[j]; }
    }
    int incl = c;
    for (int off = 1; off < 64; off <<= 1) {
      int t = __shfl_up(incl, off);
      if (lane >= off) incl += t;
    }
    if (lane == 63) wsum[wid] = incl;
    __syncthreads();
    int woff = 0;
    for (int w = 0; w < wid; ++w) woff += wsum[w];
    int k = woff + incl - c;
    for (int j = 0; j < 8; ++j)
      if (f[j]) pos[b * SL + (k++)] = base + j;
    if (tid == 255) cnt[b] = k;
    return;
  }
  __shared__ __align__(16) float sx[PROJ_ROWS * DIM];  // 16 KB (x only)
  const int row0 = blockIdx.x * PROJ_ROWS;
  for (int t = tid; t < PROJ_ROWS * 32; t += 256) {
    const int row = t >> 5, f = t & 31;
    *(float4*)&sx[row * DIM + f * 4] =
        *(const float4*)(x + (size_t)(row0 + row) * DIM + f * 4);
  }
  __syncthreads();
  const int rq = tid >> 5;        // 8 row-quads: rows rq*4 .. rq*4+3
  const int pp = (tid & 31) * 2;  // same col-pair mapping as R12
  double aq[4][2] = {}, cq[4][2] = {}, ak[4][2] = {}, ck[4][2] = {};
  for (int d = 0; d < DIM; d += 4) {
    float4 xv[4];
#pragma unroll
    for (int i = 0; i < 4; ++i)
      xv[i] = *(const float4*)&sx[(rq * 4 + i) * DIM + d];
    // W read direct from global (L1/L2-resident): same values, same order
    // as staged copies -> bit-identical chains.
    const float2 wq0 = *(const float2*)&Wq[(d + 0) * PP + pp];
    const float2 wq1 = *(const float2*)&Wq[(d + 1) * PP + pp];
    const float2 wq2 = *(const float2*)&Wq[(d + 2) * PP + pp];
    const float2 wq3 = *(const float2*)&Wq[(d + 3) * PP + pp];
    const float2 wk0 = *(const float2*)&Wk[(d + 0) * PP + pp];
    const float2 wk1 = *(const float2*)&Wk[(d + 1) * PP + pp];
    const float2 wk2 = *(const float2*)&Wk[(d + 2) * PP + pp];
    const float2 wk3 = *(const float2*)&Wk[(d + 3) * PP + pp];
#pragma unroll
    for (int i = 0; i < 4; ++i) {
      const double x0 = (double)xv[i].x, x1 = (double)xv[i].y;
      const double x2 = (double)xv[i].z, x3 = (double)xv[i].w;
      aq[i][0] += x0 * (double)wq0.x; aq[i][1] += x0 * (double)wq0.y;
      cq[i][0] += x1 * (double)wq1.x; cq[i][1] += x1 * (double)wq1.y;
      aq[i][0] += x2 * (double)wq2.x; aq[i][1] += x2 * (double)wq2.y;
      cq[i][0] += x3 * (double)wq3.x; cq[i][1] += x3 * (double)wq3.y;
      ak[i][0] += x0 * (double)wk0.x; ak[i][1] += x0 * (double)wk0.y;
      ck[i][0] += x1 * (double)wk1.x; ck[i][1] += x1 * (double)wk1.y;
      ak[i][0] += x2 * (double)wk2.x; ak[i][1] += x2 * (double)wk2.y;
      ck[i][0] += x3 * (double)wk3.x; ck[i][1] += x3 * (double)wk3.y;
    }
  }
  const double b0q = (double)bq[pp], b1q = (double)bq[pp + 1];
  const double b0k = (double)bk[pp], b1k = (double)bk[pp + 1];
#pragma unroll
  for (int i = 0; i < 4; ++i) {
    const size_t o = ((size_t)row0 + rq * 4 + i) * PP + pp;
    Q[o]     = (float)(aq[i][0] + cq[i][0] + b0q);
    Q[o + 1] = (float)(aq[i][1] + cq[i][1] + b1q);
    K[o]     = (float)(ak[i][0] + ck[i][0] + b0k);
    K[o + 1] = (float)(ak[i][1] + ck[i][1] + b1k);
  }
}

// R12/R15-VERIFIED VERBATIM score body (256 threads, 8x8 micro-tile,
// CSPLIT=4, strip = blockIdx.z slowest). 70us = established structural
// floor (R13/R16/R17/R19/R26 all regressed vs it).
__global__ __launch_bounds__(256, 2) void score_kernel(
    const float* __restrict__ Q, const float* __restrict__ K,
    const int* __restrict__ pos, const int* __restrict__ cnt,
    double* __restrict__ chunk_val, int* __restrict__ chunk_idx) {
  __shared__ __align__(16) float sQ[128 * 68];   // aliased by rval after scoring
  __shared__ __align__(16) float sK[128 * 68];
  __shared__ float cval[CAP];
  __shared__ int cidx[CAP];
  __shared__ float smax[256];
  __shared__ int spos_r[ROWS], spos_c[CTILE];
  __shared__ int cnt_sh, ovf, mcnt;
  __shared__ float thresh;

  const int b = blockIdx.y, strip = blockIdx.z, colq = blockIdx.x;
  const int tid = threadIdx.x, lane = tid & 63;
  const int nv = cnt[b];
  const int slot = (b * NSTRIP + strip) * CSPLIT + colq;
  const int r0 = strip * ROWS;
  const int per = (nv + CSPLIT - 1) / CSPLIT;
  const int cbeg = colq * per;
  const int cend = min(cbeg + per, nv);
  double* chv = chunk_val + (size_t)slot * KK;
  int* chi = chunk_idx + (size_t)slot * KK;
  if (r0 >= nv || cbeg >= cend) {
    if (tid < KK) { chv[tid] = -DBL_MAX; chi[tid] = INT_MAX; }
    return;
  }
  const int nrows = min(ROWS, nv - r0);
  if (tid < ROWS) spos_r[tid] = (tid < nrows) ? pos[b * SL + r0 + tid] : 0;
  for (int t = tid; t < 128 * 16; t += 256) {
    const int row = t >> 4, p4 = t & 15;
    float4 v = make_float4(0.f, 0.f, 0.f, 0.f);
    if (row < nrows) {
      const int g = pos[b * SL + r0 + row];
      v = *(const float4*)(Q + ((size_t)b * SL + g) * PP + p4 * 4);
    }
    *(float4*)&sQ[row * 68 + p4 * 4] = v;
  }
  if (tid == 0) { cnt_sh = 0; ovf = 0; thresh = -FLT_MAX; }
  __syncthreads();

  const int ry = tid & 15, cy = tid >> 4;   // rows ry+16i, cols cy+16j (i,j<8)

  for (int c0 = cbeg; c0 < cend; c0 += CTILE) {
    const int ncols = min(CTILE, cend - c0);
    if (tid < CTILE) spos_c[tid] = (tid < ncols) ? pos[b * SL + c0 + tid] : 0;
    for (int t = tid; t < 128 * 16; t += 256) {
      const int col = t >> 4, p4 = t & 15;
      float4 v = make_float4(0.f, 0.f, 0.f, 0.f);
      if (col < ncols) {
        const int g = pos[b * SL + c0 + col];
        v = *(const float4*)(K + ((size_t)b * SL + g) * PP + p4 * 4);
      }
      *(float4*)&sK[col * 68 + p4 * 4] = v;
    }
    __syncthreads();

    float acc[8][8] = {};
    for (int p4 = 0; p4 < 16; ++p4) {
      float4 qv[8], kv[8];
#pragma unroll
      for (int i = 0; i < 8; ++i) qv[i] = *(const float4*)&sQ[(ry + 16 * i) * 68 + p4 * 4];
#pragma unroll
      for (int j = 0; j < 8; ++j) kv[j] = *(const float4*)&sK[(cy + 16 * j) * 68 + p4 * 4];
#pragma unroll
      for (int i = 0; i < 8; ++i)
#pragma unroll
        for (int j = 0; j < 8; ++j) {
          acc[i][j] = fmaf(qv[i].x, kv[j].x, acc[i][j]);
          acc[i][j] = fmaf(qv[i].y, kv[j].y, acc[i][j]);
          acc[i][j] = fmaf(qv[i].z, kv[j].z, acc[i][j]);
          acc[i][j] = fmaf(qv[i].w, kv[j].w, acc[i][j]);
        }
    }

    if (c0 == cbeg) {
      // ---- self-seed threshold from tile 0 (verified construction) ----
      float tmax = -FLT_MAX;
      for (int i = 0; i < 8; ++i) {
        const int rr = ry + 16 * i;
        if (rr >= nrows) continue;
        for (int j = 0; j < 8; ++j) {
          const int cc = cy + 16 * j;
          if (cc >= ncols) continue;
          tmax = fmaxf(tmax, acc[i][j] * 0.125f);
        }
      }
      smax[tid] = tmax;
      __syncthreads();
      for (int k2 = 2; k2 <= 256; k2 <<= 1)
        for (int j2 = k2 >> 1; j2 >= 1; j2 >>= 1) {
          if (tid < 128) {
            const int i = ((tid & ~(j2 - 1)) << 1) | (tid & (j2 - 1));
            const int p = i | j2;
            const bool desc = ((i & k2) == 0);
            const float vi = smax[i], vp = smax[p];
            const bool sw = desc ? (vp > vi) : (vi > vp);
            if (sw) { smax[i] = vp; smax[p] = vi; }
          }
          __syncthreads();
        }
      if (tid == 0 && smax[KK - 1] > -FLT_MAX) thresh = smax[KK - 1] - MARGIN;
      __syncthreads();
    }

    // wave-granular all-or-nothing emission; overflow -> compact + retry
    bool pushed = false;
    for (int attempt = 0; attempt < 8; ++attempt) {
      const float th = thresh;
      int nloc = 0;
      for (int i = 0; i < 8; ++i) {
        const int rr = ry + 16 * i;
        if (rr >= nrows) continue;
        for (int j = 0; j < 8; ++j) {
          const int cc = cy + 16 * j;
          if (cc >= ncols) continue;
          if (acc[i][j] * 0.125f >= th) nloc++;
        }
      }
      int incl = nloc;
      for (int off = 1; off < 64; off <<= 1) {
        int t2 = __shfl_up(incl, off);
        if (lane >= off) incl += t2;
      }
      const int wtot = __shfl(incl, 63);
      if (!pushed) {
        if (wtot == 0) {
          pushed = true;
        } else {
          int wbase = 0;
          if (lane == 63) {
            wbase = atomicAdd(&cnt_sh, wtot);
            if (wbase + wtot > CAP) { atomicAdd(&cnt_sh, -wtot); wbase = -1; ovf = 1; }
          }
          wbase = __shfl(wbase, 63);
          if (wbase >= 0) {
            int sl = wbase + incl - nloc;
            for (int i = 0; i < 8; ++i) {
              const int rr = ry + 16 * i;
              if (rr >= nrows) continue;
              for (int j = 0; j < 8; ++j) {
                const int cc = cy + 16 * j;
                if (cc >= ncols) continue;
                const float s = acc[i][j] * 0.125f;
                if (s >= th) {
                  cval[sl] = s;
                  cidx[sl] = spos_r[rr] * SL + spos_c[cc];
                  ++sl;
                }
              }
            }
            pushed = true;
          }
        }
      }
      __syncthreads();
      if (ovf == 0) break;
      // ---- compaction (cold path, verified): sort fp32 buffer, raise thresh ----
      {
        const int n = cnt_sh;
        for (int j = n + tid; j < CAP; j += 256) { cval[j] = -FLT_MAX; cidx[j] = INT_MAX; }
        __syncthreads();
        for (int k2 = 2; k2 <= CAP; k2 <<= 1)
          for (int j2 = k2 >> 1; j2 >= 1; j2 >>= 1) {
            const int i = ((tid & ~(j2 - 1)) << 1) | (tid & (j2 - 1));
            const int p = i | j2;
            const bool desc = ((i & k2) == 0);
            const float vi = cval[i], vp = cval[p];
            const int ii = cidx[i], ip = cidx[p];
            const bool sw = desc ? cgt32(vp, ip, vi, ii) : cgt32(vi, ii, vp, ip);
            if (sw) { cval[i] = vp; cidx[i] = ip; cval[p] = vi; cidx[p] = ii; }
            __syncthreads();
          }
        const float t64 = cval[KK - 1];
        const float nth = (t64 > -FLT_MAX) ? (t64 - MARGIN) : thresh;
        for (int j = tid; j < CAP; j += 256) {
          const bool in = (cidx[j] != INT_MAX) && (cval[j] >= nth);
          const bool nx = (j + 1 < CAP) && (cidx[j + 1] != INT_MAX) && (cval[j + 1] >= nth);
          if (in && !nx) mcnt = j + 1;
          if (j == 0 && !in) mcnt = 0;
        }
        __syncthreads();
        if (tid == 0) { thresh = nth; cnt_sh = mcnt; ovf = 0; }
        __syncthreads();
      }
    }
    __syncthreads();  // protect sK/spos_c restage
  }

  // ---- fp64 refine (8 threads/survivor, verified) ----
  const int n = cnt_sh;
  double* rval = (double*)sQ;  // alias: sQ dead after scoring
  for (int base2 = 0; base2 < n; base2 += 32) {
    const int s = base2 + (tid >> 3);
    double p = 0;
    if (s < n) {
      const int fi = cidx[s];
      const int orow = fi >> 11, ocol = fi & (SL - 1);
      const float* qr = Q + ((size_t)b * SL + orow) * PP + (tid & 7) * 8;
      const float* kr = K + ((size_t)b * SL + ocol) * PP + (tid & 7) * 8;
#pragma unroll
      for (int e = 0; e < 8; ++e) p = fma((double)qr[e], (double)kr[e], p);
    }
    p += __shfl_down(p, 4);
    p += __shfl_down(p, 2);
    p += __shfl_down(p, 1);
    if (((tid & 7) == 0) && s < n) rval[s] = p * 0.125;
  }
  // ---- adaptive LDS bitonic (verified) + top-64 out ----
  int np2 = KK;
  while (np2 < n) np2 <<= 1;  // n <= CAP
  for (int j = n + tid; j < np2; j += 256) { rval[j] = -DBL_MAX; cidx[j] = INT_MAX; }
  __syncthreads();
  for (int k2 = 2; k2 <= np2; k2 <<= 1)
    for (int j2 = k2 >> 1; j2 >= 1; j2 >>= 1) {
      if (tid < (np2 >> 1)) {
        const int i = ((tid & ~(j2 - 1)) << 1) | (tid & (j2 - 1));
        const int p = i | j2;
        const bool desc = ((i & k2) == 0);
        const double vi = rval[i], vp = rval[p];
        const int ii = cidx[i], ip = cidx[p];
        const bool sw = desc ? cgt64(vp, ip, vi, ii) : cgt64(vi, ii, vp, ip);
        if (sw) { rval[i] = vp; cidx[i] = ip; rval[p] = vi; cidx[p] = ii; }
      }
      __syncthreads();
    }
  if (tid < KK) { chv[tid] = rval[tid]; chi[tid] = cidx[tid]; }
}

// R11/R12-VERIFIED VERBATIM. 64-way merge of sorted lists, fp64 softmax, outputs.
__global__ __launch_bounds__(256) void merge_kernel(
    const double* __restrict__ chunk_val, const int* __restrict__ chunk_idx,
    float* __restrict__ out) {
  __shared__ double sval[NSLOT * 16];
  __shared__ int sidx[NSLOT * 16];
  const int b = blockIdx.x, tid = threadIdx.x;
  const double* vb = chunk_val + (size_t)b * NSLOT * KK;
  const int* ib = chunk_idx + (size_t)b * NSLOT * KK;
  for (int t = tid; t < NSLOT * 16; t += 256) {
    const int list = t >> 4, e = t & 15;
    sval[t] = vb[list * KK + e];
    sidx[t] = ib[list * KK + e];
  }
  __syncthreads();
  if (tid < 64) {
    const int lane = tid;
    int hp = 0;
    double cur = sval[lane * 16];
    int curi = sidx[lane * 16];
    double myv = -DBL_MAX; int myi = INT_MAX;
    for (int k = 0; k < KK; ++k) {
      double bv = cur; int bi = curi; int bg = lane;
      for (int off2 = 32; off2 > 0; off2 >>= 1) {
        const double v2 = __shfl_down(bv, off2);
        const int i2 = __shfl_down(bi, off2);
        const int g2 = __shfl_down(bg, off2);
        if (cgt64(v2, i2, bv, bi)) { bv = v2; bi = i2; bg = g2; }
      }
      bv = __shfl(bv, 0); bi = __shfl(bi, 0); bg = __shfl(bg, 0);
      if (bg == lane) {
        const int h = ++hp;
        if (h < 16) { cur = sval[lane * 16 + h]; curi = sidx[lane * 16 + h]; }
        else if (h < KK) { cur = vb[lane * KK + h]; curi = ib[lane * KK + h]; }
        else { cur = -DBL_MAX; curi = INT_MAX; }
      }
      if (lane == k) { myv = bv; myi = bi; }
    }
    const double m = __shfl(myv, 0);
    double e = (myi == INT_MAX || myv == -DBL_MAX) ? 0.0 : exp(myv - m);
    double s = e;
    for (int off2 = 32; off2 > 0; off2 >>= 1) s += __shfl_down(s, off2);
    s = __shfl(s, 0);
    if (s <= 0.0) s = 1.0;
    const double w = e / s;
    int row = 0, col = 0;
    if (myi != INT_MAX) { row = myi >> 11; col = myi & (SL - 1); }
    float* oidx = out;
    float* owt = out + (size_t)NB * KK * 2;
    oidx[((size_t)b * KK + lane) * 2 + 0] = (float)row;
    oidx[((size_t)b * KK + lane) * 2 + 1] = (float)col;
    owt[(size_t)b * KK + lane] = (float)w;
  }
}

}  // namespace

extern "C" void kernel_launch(void* const* d_in, const int* in_sizes, int n_in,
                              void* d_out, int out_size, void* d_ws, size_t ws_size,
                              hipStream_t stream) {
  const float* x = (const float*)d_in[0];
  const void* mask_raw = d_in[1];
  const float* Wq = (const float*)d_in[2];
  const float* bq = (const float*)d_in[3];
  const float* Wk = (const float*)d_in[4];
  const float* bk = (const float*)d_in[5];
  float* out = (float*)d_out;

  char* ws = (char*)d_ws;
  const size_t qk = (size_t)NB * SL * PP;  // 1,048,576 elems
  float* Q = (float*)ws;                                            // 4 MB
  float* K = (float*)(ws + qk * 4);                                 // 4 MB
  size_t off = qk * 8;
  double* chunk_val = (double*)(ws + off); off += (size_t)NB * NSLOT * KK * 8;  // 256 KB
  int* chunk_idx = (int*)(ws + off);       off += (size_t)NB * NSLOT * KK * 4;  // 128 KB
  int* pos = (int*)(ws + off);             off += (size_t)NB * SL * 4;          // 64 KB
  int* cntv = (int*)(ws + off);            // total ~8.45 MB

  // R23-verified proj (256 threads, 4 rows/thread, W from global).
  proj_compact_kernel<<<NPROJ + NB, 256, 0, stream>>>(
      x, mask_raw, Wq, bq, Wk, bk, Q, K, pos, cntv);
  // R15 packing (verified best): strip = blockIdx.z (slowest) -> active
  // blocks contiguous in dispatch order, spread 1-per-CU.
  score_kernel<<<dim3(CSPLIT, NB, NSTRIP), 256, 0, stream>>>(
      Q, K, pos, cntv, chunk_val, chunk_idx);
  merge_kernel<<<NB, 256, 0, stream>>>(chunk_val, chunk_idx, out);
}